// Round 3
// baseline (9342.929 us; speedup 1.0000x reference)
//
#include <hip/hip_runtime.h>
#include <hip/hip_bf16.h>
#include <hip/hip_fp16.h>
#include <cstdint>
#include <cstddef>

#define AS1 __attribute__((address_space(1)))
#define AS3 __attribute__((address_space(3)))

constexpr int HIDC   = 4096;
constexpr int INTERC = 11008;
constexpr int NTOKC  = 4096;          // B*S
constexpr int NWGU   = 2 * INTERC;    // 22016 gate_up weight cols

using f32x4 = __attribute__((ext_vector_type(4))) float;
using f16x8 = __attribute__((ext_vector_type(8))) _Float16;

// ---------------- prologue kernels ----------------

// x f32 -> f16
__global__ void cvt_x_kernel(const float4* __restrict__ x, ushort4* __restrict__ xh, int n4) {
  int stride = gridDim.x * blockDim.x;
  for (int i = blockIdx.x * blockDim.x + threadIdx.x; i < n4; i += stride) {
    float4 v = x[i];
    ushort4 o;
    o.x = __builtin_bit_cast(unsigned short, __float2half(v.x));
    o.y = __builtin_bit_cast(unsigned short, __float2half(v.y));
    o.z = __builtin_bit_cast(unsigned short, __float2half(v.z));
    o.w = __builtin_bit_cast(unsigned short, __float2half(v.w));
    xh[i] = o;
  }
}

// repack qweight [K][N/8] (nibbles along N) -> qt [K/32][N][4] (k-tile-major,
// coalesced per-tile reads). Nibble order within each qword is PERMUTED:
// k=j lands at pos (j&1)?4+(j>>1):(j>>1) so (q>>4i)&0x000F000F = k-pair (2i,2i+1).
__global__ void repack_kernel(const uint32_t* __restrict__ qw, uint32_t* __restrict__ qt,
                              int K32, int Wn8) {
  long total  = (long)K32 * Wn8;
  long stride = (long)gridDim.x * blockDim.x;
  for (long idx = blockIdx.x * (long)blockDim.x + threadIdx.x; idx < total; idx += stride) {
    int kt2 = (int)(idx / Wn8);
    int cg  = (int)(idx - (long)kt2 * Wn8);
    uint32_t ow[8][4] = {};
#pragma unroll
    for (int kl = 0; kl < 32; ++kl) {
      uint32_t v = qw[(size_t)(kt2 * 32 + kl) * Wn8 + cg];
      const int kkl = kl >> 3, j = kl & 7;
      const int pos = (j & 1) ? (4 + (j >> 1)) : (j >> 1);
#pragma unroll
      for (int c = 0; c < 8; ++c)
        ow[c][kkl] |= ((v >> (4 * c)) & 0xFu) << (4 * pos);
    }
    uint4* dst = (uint4*)(qt + ((size_t)kt2 * Wn8 * 8 + (size_t)cg * 8) * 4);
#pragma unroll
    for (int c = 0; c < 8; ++c)
      dst[c] = make_uint4(ow[c][0], ow[c][1], ow[c][2], ow[c][3]);
  }
}

// tab[g][n] = ( half2(s,s), half2(-z*s,-z*s) ) packed as uint2
__global__ void mktab_kernel(const uint32_t* __restrict__ qz, const float* __restrict__ sc,
                             uint2* __restrict__ tab, int total, int Nw) {
  int stride = gridDim.x * blockDim.x;
  for (int idx = blockIdx.x * blockDim.x + threadIdx.x; idx < total; idx += stride) {
    int g = idx / Nw, n = idx - g * Nw;
    uint32_t z = (qz[(size_t)g * (Nw >> 3) + (n >> 3)] >> ((n & 7) * 4)) & 0xFu;
    float s = sc[idx];
    uint32_t us = (uint32_t)__builtin_bit_cast(unsigned short, __float2half(s));
    uint32_t uc = (uint32_t)__builtin_bit_cast(unsigned short, __float2half(-s * (float)z));
    tab[idx] = make_uint2(us | (us << 16), uc | (uc << 16));
  }
}

// ---------------- fused dequant GEMM, 256x256, counted-vmcnt pipeline ----------------
// 512 threads = 8 waves (2M x 4N), per-wave 128x64 output, BK=64.
// LDS 128KB: 2 buffers x (A 32KB + B 32KB). XOR swizzle byte^=(row&7)<<4.
// Per K-tile: issue stage(kt+1)[4 gload_lds] + q/tab(kt+3)[2 loads], dequant(kt+1)
// from 2-deep reg prefetch, compute(kt), then s_waitcnt vmcnt(2) (A staged, q/tab
// STAY IN FLIGHT across the barrier) + raw s_barrier. Never vmcnt(0) in the loop.
template <int DUAL, int NT, int NWTOT, int NXT, int K>
__global__ __launch_bounds__(512, 2) void qgemm_kernel(
    const __half* __restrict__ A, const uint32_t* __restrict__ QT,
    const uint2* __restrict__ TAB, __half* __restrict__ Hout,
    float* __restrict__ Fout) {
  __shared__ __align__(16) char lds[131072];

  const int tid  = threadIdx.x;
  const int lane = tid & 63;
  const int w    = tid >> 6;
  const int wr   = w >> 2, wc = w & 3;
  const int fr   = lane & 15;
  const int fq   = lane >> 4;

  // bijective XCD chunking (grid%8==0): N varies fastest within a chunk.
  const int nwg8 = (int)gridDim.x >> 3;
  const int g2   = (blockIdx.x & 7) * nwg8 + ((int)blockIdx.x >> 3);
  const int mt   = g2 / NXT;
  const int nt   = g2 - mt * NXT;
  const int row0 = mt * 256;

  // A staging: linear LDS dest, pre-swizzled global source.
  int a_src[4];
#pragma unroll
  for (int i = 0; i < 4; ++i) {
    int o = i * 8192 + tid * 16;
    int r = o >> 7;
    int b = (o & 127) ^ ((r & 7) << 4);
    a_src[i] = (row0 + r) * K + (b >> 1);
  }

  // B staging: thread owns tile-col tc (wave-contiguous for coalesced q loads),
  // k-half kh (32 nibbles = one uint4).
  const int tc = tid & 255, kh = tid >> 8;
  int wcol;
  if (DUAL) {
    const int p = tc >> 5, mat = (tc >> 4) & 1, c16 = tc & 15;
    wcol = nt * 128 + p * 16 + c16 + mat * INTERC;
  } else {
    wcol = nt * 256 + tc;
  }
  const int boff = 32768 + tc * 128;
  const int bswz = (tc & 7) << 4;

  auto qaddr = [&](int t) {   // tile t, this thread's k-half
    return (const uint4*)(QT + ((size_t)(2 * t + kh) * NWTOT + wcol) * 4);
  };
  auto taddr = [&](int t) { return TAB + (size_t)(t >> 1) * NWTOT + wcol; };

  f32x4 acc[8][4] = {};

  auto stageA = [&](int kt, int buf) {
#pragma unroll
    for (int i = 0; i < 4; ++i)
      __builtin_amdgcn_global_load_lds((const AS1 uint32_t*)(A + a_src[i] + kt * 64),
                                       (AS3 uint32_t*)(lds + buf * 65536 + i * 8192 + w * 1024),
                                       16, 0, 0);
  };

  auto dequantB = [&](uint4 q, uint2 tz, int buf) {
    const __half2 s2 = __builtin_bit_cast(__half2, tz.x);
    const __half2 c2 = __builtin_bit_cast(__half2, tz.y);
    const __half2 k1024 = __builtin_bit_cast(__half2, 0x64006400u);
    char* bd = lds + buf * 65536 + boff;
    uint32_t qq[4] = {q.x, q.y, q.z, q.w};
#pragma unroll
    for (int ii = 0; ii < 4; ++ii) {
      uint32_t r[4];
#pragma unroll
      for (int i = 0; i < 4; ++i) {
        uint32_t pr = ((qq[ii] >> (4 * i)) & 0x000F000Fu) | 0x64006400u;
        __half2 t  = __hsub2(__builtin_bit_cast(__half2, pr), k1024);  // exact nibble pair
        __half2 wv = __hfma2(t, s2, c2);                               // n*s - z*s
        r[i] = __builtin_bit_cast(uint32_t, wv);
      }
      *(uint4*)(bd + ((kh * 64 + ii * 16) ^ bswz)) = make_uint4(r[0], r[1], r[2], r[3]);
    }
  };

  auto compute = [&](int buf) {
    const char* base = lds + buf * 65536;
#pragma unroll
    for (int kk = 0; kk < 2; ++kk) {
      const int bb = (((kk << 2) | fq) ^ (fr & 7)) << 4;
      f16x8 av[8], bv[4];
#pragma unroll
      for (int mi = 0; mi < 8; ++mi)
        av[mi] = *(const f16x8*)(base + (wr * 128 + mi * 16 + fr) * 128 + bb);
#pragma unroll
      for (int ni = 0; ni < 4; ++ni)
        bv[ni] = *(const f16x8*)(base + 32768 + (wc * 64 + ni * 16 + fr) * 128 + bb);
      __builtin_amdgcn_s_setprio(1);
#pragma unroll
      for (int mi = 0; mi < 8; ++mi)
#pragma unroll
        for (int ni = 0; ni < 4; ++ni)
          acc[mi][ni] = __builtin_amdgcn_mfma_f32_16x16x32_f16(av[mi], bv[ni], acc[mi][ni], 0, 0, 0);
      __builtin_amdgcn_s_setprio(0);
    }
  };

  // ---- prologue: tile 0 staged+dequantized; q-prefetch 2 deep ----
  stageA(0, 0);
  __builtin_amdgcn_sched_barrier(0);
  uint4 q0  = *qaddr(0);
  uint2 t0  = *taddr(0);
  uint4 qcur = *qaddr(1);  uint2 tzcur = *taddr(1);
  uint4 qn1  = *qaddr(2);  uint2 tn1   = *taddr(2);
  __builtin_amdgcn_sched_barrier(0);
  dequantB(q0, t0, 0);
  // queue: stage0 x4, q0,t0, qcur,tzcur, qn1,tn1 -> vmcnt(2)? dequant already
  // waited to pos of t0 (vmcnt(4)); wait vmcnt(2) retires qcur/tzcur too,
  // leaving qn1/tn1 in flight == steady-state entry invariant.
  asm volatile("s_waitcnt vmcnt(2) lgkmcnt(0)\n\ts_barrier" ::: "memory");

  int cur = 0;
#pragma unroll 1
  for (int kt = 0; kt < NT; ++kt) {
    if (kt + 1 < NT) {
      stageA(kt + 1, cur ^ 1);                       // 4 vm loads (oldest this iter)
      __builtin_amdgcn_sched_barrier(0);             // pin: stage before q/tab
      const int kn = (kt + 3 < NT) ? kt + 3 : NT - 1;
      uint4 qn = *qaddr(kn);                         // 2 vm loads (newest)
      uint2 tn = *taddr(kn);
      __builtin_amdgcn_sched_barrier(0);
      dequantB(qcur, tzcur, cur ^ 1);                // q(kt+1): retired last iter
      compute(cur);
      qcur = qn1; tzcur = tn1; qn1 = qn; tn1 = tn;
      // retire stage(kt+1) (+ anything older); q/tab(kt+3) stay in flight.
      asm volatile("s_waitcnt vmcnt(2) lgkmcnt(0)\n\ts_barrier" ::: "memory");
    } else {
      compute(cur);
    }
    cur ^= 1;
  }

  // ---- epilogue — C/D map: col = lane&15 (fr), row = fq*4 + reg ----
  if (DUAL) {
#pragma unroll
    for (int mi = 0; mi < 8; ++mi) {
      const int rr = row0 + wr * 128 + mi * 16 + fq * 4;
#pragma unroll
      for (int pp = 0; pp < 2; ++pp) {
        const int hcol = nt * 128 + (wc * 2 + pp) * 16 + fr;
#pragma unroll
        for (int r = 0; r < 4; ++r) {
          float gv = acc[mi][2 * pp][r];
          float uv = acc[mi][2 * pp + 1][r];
          float hv = gv / (1.0f + __expf(-gv)) * uv;
          Hout[(size_t)(rr + r) * INTERC + hcol] = __float2half(hv);
        }
      }
    }
  } else {
#pragma unroll
    for (int mi = 0; mi < 8; ++mi) {
      const int rr = row0 + wr * 128 + mi * 16 + fq * 4;
#pragma unroll
      for (int ni = 0; ni < 4; ++ni) {
        const int cc = nt * 256 + wc * 64 + ni * 16 + fr;
#pragma unroll
        for (int r = 0; r < 4; ++r)
          Fout[(size_t)(rr + r) * HIDC + cc] = acc[mi][ni][r];
      }
    }
  }
}

// ---------------- launch ----------------
extern "C" void kernel_launch(void* const* d_in, const int* in_sizes, int n_in,
                              void* d_out, int out_size, void* d_ws, size_t ws_size,
                              hipStream_t stream) {
  const float*    x     = (const float*)d_in[0];
  const uint32_t* qw_gu = (const uint32_t*)d_in[1];
  const uint32_t* qz_gu = (const uint32_t*)d_in[2];
  const float*    sc_gu = (const float*)d_in[3];
  const uint32_t* qw_dn = (const uint32_t*)d_in[4];
  const uint32_t* qz_dn = (const uint32_t*)d_in[5];
  const float*    sc_dn = (const float*)d_in[6];
  float* out = (float*)d_out;

  // workspace layout (bytes), ~199.8 MB
  char* ws = (char*)d_ws;
  __half*   xh   = (__half*)(ws + 0);                 // 33,554,432
  uint32_t* qtgu = (uint32_t*)(ws + 33554432);        // 45,088,768
  uint32_t* qtdn = (uint32_t*)(ws + 78643200);        // 22,544,384
  uint2*    tgu  = (uint2*)(ws + 101187584);          //  5,636,096
  uint2*    tdn  = (uint2*)(ws + 106823680);          //  2,818,048
  __half*   hbuf = (__half*)(ws + 109641728);         // 90,177,536

  cvt_x_kernel<<<2048, 256, 0, stream>>>((const float4*)x, (ushort4*)xh, NTOKC * HIDC / 4);
  repack_kernel<<<2048, 256, 0, stream>>>(qw_gu, qtgu, HIDC / 32, NWGU / 8);
  repack_kernel<<<2048, 256, 0, stream>>>(qw_dn, qtdn, INTERC / 32, HIDC / 8);
  mktab_kernel<<<1024, 256, 0, stream>>>(qz_gu, sc_gu, tgu, (HIDC / 128) * NWGU, NWGU);
  mktab_kernel<<<1024, 256, 0, stream>>>(qz_dn, sc_dn, tdn, (INTERC / 128) * HIDC, HIDC);

  // GEMM1: x[4096x4096] @ W_gu -> silu*mul -> h f16 [4096x11008]; 86x16=1376 blocks
  qgemm_kernel<1, 64, NWGU, 86, HIDC>
      <<<1376, 512, 0, stream>>>(xh, qtgu, tgu, hbuf, nullptr);
  // GEMM2: h @ W_dn -> out f32 [4096x4096]; 16x16=256 blocks
  qgemm_kernel<0, 172, HIDC, 16, INTERC>
      <<<256, 512, 0, stream>>>(hbuf, qtdn, tdn, nullptr, out);
}

// Round 4
// 1390.616 us; speedup vs baseline: 6.7186x; 6.7186x over previous
//
#include <hip/hip_runtime.h>
#include <hip/hip_bf16.h>
#include <hip/hip_fp16.h>
#include <cstdint>
#include <cstddef>

#define AS1 __attribute__((address_space(1)))
#define AS3 __attribute__((address_space(3)))

constexpr int HIDC   = 4096;
constexpr int INTERC = 11008;
constexpr int NTOKC  = 4096;          // B*S
constexpr int NWGU   = 2 * INTERC;    // 22016 gate_up weight cols

using f32x4 = __attribute__((ext_vector_type(4))) float;
using f16x8 = __attribute__((ext_vector_type(8))) _Float16;

// ---------------- prologue kernels ----------------

__global__ void cvt_x_kernel(const float4* __restrict__ x, ushort4* __restrict__ xh, int n4) {
  int stride = gridDim.x * blockDim.x;
  for (int i = blockIdx.x * blockDim.x + threadIdx.x; i < n4; i += stride) {
    float4 v = x[i];
    ushort4 o;
    o.x = __builtin_bit_cast(unsigned short, __float2half(v.x));
    o.y = __builtin_bit_cast(unsigned short, __float2half(v.y));
    o.z = __builtin_bit_cast(unsigned short, __float2half(v.z));
    o.w = __builtin_bit_cast(unsigned short, __float2half(v.w));
    xh[i] = o;
  }
}

// repack qweight [K][N/8] (nibbles along N) -> qt [K/32][N][4] (k-tile-major).
// Nibble order within each qword PERMUTED: k=j at pos (j&1)?4+(j>>1):(j>>1),
// so (q>>4i)&0x000F000F extracts the k-pair (2i,2i+1).
__global__ void repack_kernel(const uint32_t* __restrict__ qw, uint32_t* __restrict__ qt,
                              int K32, int Wn8) {
  long total  = (long)K32 * Wn8;
  long stride = (long)gridDim.x * blockDim.x;
  for (long idx = blockIdx.x * (long)blockDim.x + threadIdx.x; idx < total; idx += stride) {
    int kt2 = (int)(idx / Wn8);
    int cg  = (int)(idx - (long)kt2 * Wn8);
    uint32_t ow[8][4] = {};
#pragma unroll
    for (int kl = 0; kl < 32; ++kl) {
      uint32_t v = qw[(size_t)(kt2 * 32 + kl) * Wn8 + cg];
      const int kkl = kl >> 3, j = kl & 7;
      const int pos = (j & 1) ? (4 + (j >> 1)) : (j >> 1);
#pragma unroll
      for (int c = 0; c < 8; ++c)
        ow[c][kkl] |= ((v >> (4 * c)) & 0xFu) << (4 * pos);
    }
    uint4* dst = (uint4*)(qt + ((size_t)kt2 * Wn8 * 8 + (size_t)cg * 8) * 4);
#pragma unroll
    for (int c = 0; c < 8; ++c)
      dst[c] = make_uint4(ow[c][0], ow[c][1], ow[c][2], ow[c][3]);
  }
}

// tab[g][n] = ( half2(s,s), half2(-z*s,-z*s) ) packed as uint2
__global__ void mktab_kernel(const uint32_t* __restrict__ qz, const float* __restrict__ sc,
                             uint2* __restrict__ tab, int total, int Nw) {
  int stride = gridDim.x * blockDim.x;
  for (int idx = blockIdx.x * blockDim.x + threadIdx.x; idx < total; idx += stride) {
    int g = idx / Nw, n = idx - g * Nw;
    uint32_t z = (qz[(size_t)g * (Nw >> 3) + (n >> 3)] >> ((n & 7) * 4)) & 0xFu;
    float s = sc[idx];
    uint32_t us = (uint32_t)__builtin_bit_cast(unsigned short, __float2half(s));
    uint32_t uc = (uint32_t)__builtin_bit_cast(unsigned short, __float2half(-s * (float)z));
    tab[idx] = make_uint2(us | (us << 16), uc | (uc << 16));
  }
}

// ---------------- fused dequant GEMM, 256x256, 8-phase (m201-style) ----------------
// 512 threads = 8 waves (2M x 4N), per-wave 128x64 output, BK=64, 4 phases/K-tile.
// Phase p (kk=p>>1, mh=p&1): ds_read frags | stage/dequant slice for kt+1 |
// barrier; lgkmcnt(0); sched_barrier; setprio(1); 16 MFMA; setprio(0); barrier.
// Tile-end: counted s_waitcnt vmcnt(2) (A-stage retired, q/tab stay in flight).

#define GLOAD(i, KT)                                                             \
  __builtin_amdgcn_global_load_lds(                                              \
      (const AS1 uint32_t*)(A + a_src[i] + ((KT) + 1) * 64),                     \
      (AS3 uint32_t*)(lds + (cur_ ^ 1) * 65536 + (i) * 8192 + w * 1024), 16, 0, 0)

#define DEQ_WORD(p, DSTBUF)                                                      \
  {                                                                              \
    char* bd_ = lds + (DSTBUF) * 65536 + boff;                                   \
    uint32_t r_[4];                                                              \
    _Pragma("unroll")                                                            \
    for (int i_ = 0; i_ < 4; ++i_) {                                             \
      uint32_t pr_ = ((qw_[p] >> (4 * i_)) & 0x000F000Fu) | 0x64006400u;         \
      __half2 t_  = __hsub2(__builtin_bit_cast(__half2, pr_), kk1024_);          \
      __half2 wv_ = __hfma2(t_, s2_, c2_);                                       \
      r_[i_] = __builtin_bit_cast(uint32_t, wv_);                                \
    }                                                                            \
    *(uint4*)(bd_ + (((kh) * 64 + (p) * 16) ^ bswz)) =                           \
        make_uint4(r_[0], r_[1], r_[2], r_[3]);                                  \
  }

#define PHASE(p, STG, PRF, KT, QLAND, TLAND)                                     \
  {                                                                              \
    const char* rb_ = lds + cur_ * 65536;                                        \
    const int bb_ = (((((p) >> 1) << 2) | fq) ^ (fr & 7)) << 4;                  \
    if (((p) & 1) == 0) {                                                        \
      _Pragma("unroll")                                                          \
      for (int ni_ = 0; ni_ < 4; ++ni_)                                          \
        bv[ni_] = *(const f16x8*)(rb_ + 32768 + (wc * 64 + ni_ * 16 + fr) * 128 + bb_); \
    }                                                                            \
    _Pragma("unroll")                                                            \
    for (int j_ = 0; j_ < 4; ++j_)                                               \
      av[j_] = *(const f16x8*)(rb_ + (wr * 128 + (((p) & 1) * 4 + j_) * 16 + fr) * 128 + bb_); \
    if (STG) {                                                                   \
      if ((p) == 0) { GLOAD(0, KT); GLOAD(1, KT); }                              \
      if ((p) == 1) { GLOAD(2, KT); GLOAD(3, KT); }                              \
      if ((p) == 2 && (PRF)) { QLAND = *qaddr((KT) + 2); TLAND = *taddr((KT) + 2); } \
      DEQ_WORD(p, cur_ ^ 1)                                                      \
    }                                                                            \
    asm volatile("s_barrier" ::: "memory");                                      \
    asm volatile("s_waitcnt lgkmcnt(0)" ::: "memory");                           \
    __builtin_amdgcn_sched_barrier(0);                                           \
    __builtin_amdgcn_s_setprio(1);                                               \
    _Pragma("unroll")                                                            \
    for (int j_ = 0; j_ < 4; ++j_)                                               \
      _Pragma("unroll")                                                          \
      for (int ni_ = 0; ni_ < 4; ++ni_)                                          \
        acc[((p) & 1) * 4 + j_][ni_] = __builtin_amdgcn_mfma_f32_16x16x32_f16(   \
            av[j_], bv[ni_], acc[((p) & 1) * 4 + j_][ni_], 0, 0, 0);             \
    __builtin_amdgcn_s_setprio(0);                                               \
    if ((p) < 3)                                                                 \
      asm volatile("s_barrier" ::: "memory");                                    \
    else if ((STG) && (PRF))                                                     \
      asm volatile("s_waitcnt vmcnt(2) lgkmcnt(0)\n\ts_barrier" ::: "memory");   \
    else if (STG)                                                                \
      asm volatile("s_waitcnt vmcnt(0) lgkmcnt(0)\n\ts_barrier" ::: "memory");   \
    else                                                                         \
      asm volatile("s_waitcnt lgkmcnt(0)\n\ts_barrier" ::: "memory");            \
  }

#define TILE(CUR, QUSE, TUSE, QLAND, TLAND, KT, STG, PRF)                        \
  {                                                                              \
    const int cur_ = (CUR);                                                      \
    const __half2 kk1024_ = __builtin_bit_cast(__half2, 0x64006400u);            \
    uint32_t qw_[4] = {};                                                        \
    __half2 s2_ = kk1024_, c2_ = kk1024_;                                        \
    if (STG) {                                                                   \
      qw_[0] = (QUSE).x; qw_[1] = (QUSE).y; qw_[2] = (QUSE).z; qw_[3] = (QUSE).w;\
      s2_ = __builtin_bit_cast(__half2, (TUSE).x);                               \
      c2_ = __builtin_bit_cast(__half2, (TUSE).y);                               \
    }                                                                            \
    f16x8 av[4], bv[4];                                                          \
    PHASE(0, STG, PRF, KT, QLAND, TLAND)                                         \
    PHASE(1, STG, PRF, KT, QLAND, TLAND)                                         \
    PHASE(2, STG, PRF, KT, QLAND, TLAND)                                         \
    PHASE(3, STG, PRF, KT, QLAND, TLAND)                                         \
  }

template <int DUAL, int NT, int NWTOT, int NXT, int K>
__global__ __launch_bounds__(512, 1) void qgemm_kernel(
    const __half* __restrict__ A, const uint32_t* __restrict__ QT,
    const uint2* __restrict__ TAB, __half* __restrict__ Hout,
    float* __restrict__ Fout) {
  __shared__ __align__(16) char lds[131072];

  const int tid  = threadIdx.x;
  const int lane = tid & 63;
  const int w    = tid >> 6;
  const int wr   = w >> 2, wc = w & 3;
  const int fr   = lane & 15;
  const int fq   = lane >> 4;

  // bijective XCD chunking (grid%8==0): N varies fastest within a chunk.
  const int nwg8 = (int)gridDim.x >> 3;
  const int g2   = (blockIdx.x & 7) * nwg8 + ((int)blockIdx.x >> 3);
  const int mt   = g2 / NXT;
  const int nt   = g2 - mt * NXT;
  const int row0 = mt * 256;

  // A staging: linear LDS dest, pre-swizzled global source (swz byte^=(row&7)<<4).
  int a_src[4];
#pragma unroll
  for (int i = 0; i < 4; ++i) {
    int o = i * 8192 + tid * 16;
    int r = o >> 7;
    int b = (o & 127) ^ ((r & 7) << 4);
    a_src[i] = (row0 + r) * K + (b >> 1);
  }

  // B staging: thread owns tile-col tc, k-half kh (one uint4 = 32 nibbles).
  const int tc = tid & 255, kh = tid >> 8;
  int wcol;
  if (DUAL) {
    const int p = tc >> 5, mat = (tc >> 4) & 1, c16 = tc & 15;
    wcol = nt * 128 + p * 16 + c16 + mat * INTERC;
  } else {
    wcol = nt * 256 + tc;
  }
  const int boff = 32768 + tc * 128;
  const int bswz = (tc & 7) << 4;

  auto qaddr = [&](int t) {
    return (const uint4*)(QT + ((size_t)(2 * t + kh) * NWTOT + wcol) * 4);
  };
  auto taddr = [&](int t) { return TAB + (size_t)(t >> 1) * NWTOT + wcol; };

  f32x4 acc[8][4] = {};

  // ---- prologue: tile 0 into buf0; q(1) in flight ----
  uint4 qA, qB; uint2 tA, tB;
  uint4 q0  = *qaddr(0);
  uint2 t0v = *taddr(0);
  {
    const int cur_ = 1;            // cur_^1 == 0 => stage into buf0
    GLOAD(0, -1); GLOAD(1, -1); GLOAD(2, -1); GLOAD(3, -1);
  }
  __builtin_amdgcn_sched_barrier(0);   // pin: stages issued before q(1)/tab(1)
  qB = *qaddr(1); tB = *taddr(1);
  __builtin_amdgcn_sched_barrier(0);
  {
    const __half2 kk1024_ = __builtin_bit_cast(__half2, 0x64006400u);
    const __half2 s2_ = __builtin_bit_cast(__half2, t0v.x);
    const __half2 c2_ = __builtin_bit_cast(__half2, t0v.y);
    uint32_t qw_[4] = {q0.x, q0.y, q0.z, q0.w};
    DEQ_WORD(0, 0) DEQ_WORD(1, 0) DEQ_WORD(2, 0) DEQ_WORD(3, 0)
  }
  asm volatile("s_waitcnt vmcnt(2) lgkmcnt(0)\n\ts_barrier" ::: "memory");

  // ---- main loop: 2 tiles (8 phases) per iteration ----
#pragma unroll 1
  for (int kt2 = 0; kt2 < NT / 2 - 1; ++kt2) {
    TILE(0, qB, tB, qA, tA, 2 * kt2, 1, 1)
    TILE(1, qA, tA, qB, tB, 2 * kt2 + 1, 1, 1)
  }
  TILE(0, qB, tB, qA, tA, NT - 2, 1, 0)
  TILE(1, qA, tA, qB, tB, NT - 1, 0, 0)

  // ---- epilogue — C/D map: col = lane&15 (fr), row = fq*4 + reg ----
  if (DUAL) {
#pragma unroll
    for (int mi = 0; mi < 8; ++mi) {
      const int rr = row0 + wr * 128 + mi * 16 + fq * 4;
#pragma unroll
      for (int pp = 0; pp < 2; ++pp) {
        const int hcol = nt * 128 + (wc * 2 + pp) * 16 + fr;
#pragma unroll
        for (int r = 0; r < 4; ++r) {
          float gv = acc[mi][2 * pp][r];
          float uv = acc[mi][2 * pp + 1][r];
          float hv = gv / (1.0f + __expf(-gv)) * uv;
          Hout[(size_t)(rr + r) * INTERC + hcol] = __float2half(hv);
        }
      }
    }
  } else {
#pragma unroll
    for (int mi = 0; mi < 8; ++mi) {
      const int rr = row0 + wr * 128 + mi * 16 + fq * 4;
#pragma unroll
      for (int ni = 0; ni < 4; ++ni) {
        const int cc = nt * 256 + wc * 64 + ni * 16 + fr;
#pragma unroll
        for (int r = 0; r < 4; ++r)
          Fout[(size_t)(rr + r) * HIDC + cc] = acc[mi][ni][r];
      }
    }
  }
}

// ---------------- launch ----------------
extern "C" void kernel_launch(void* const* d_in, const int* in_sizes, int n_in,
                              void* d_out, int out_size, void* d_ws, size_t ws_size,
                              hipStream_t stream) {
  const float*    x     = (const float*)d_in[0];
  const uint32_t* qw_gu = (const uint32_t*)d_in[1];
  const uint32_t* qz_gu = (const uint32_t*)d_in[2];
  const float*    sc_gu = (const float*)d_in[3];
  const uint32_t* qw_dn = (const uint32_t*)d_in[4];
  const uint32_t* qz_dn = (const uint32_t*)d_in[5];
  const float*    sc_dn = (const float*)d_in[6];
  float* out = (float*)d_out;

  // workspace layout (bytes), ~199.8 MB
  char* ws = (char*)d_ws;
  __half*   xh   = (__half*)(ws + 0);                 // 33,554,432
  uint32_t* qtgu = (uint32_t*)(ws + 33554432);        // 45,088,768
  uint32_t* qtdn = (uint32_t*)(ws + 78643200);        // 22,544,384
  uint2*    tgu  = (uint2*)(ws + 101187584);          //  5,636,096
  uint2*    tdn  = (uint2*)(ws + 106823680);          //  2,818,048
  __half*   hbuf = (__half*)(ws + 109641728);         // 90,177,536

  cvt_x_kernel<<<2048, 256, 0, stream>>>((const float4*)x, (ushort4*)xh, NTOKC * HIDC / 4);
  repack_kernel<<<2048, 256, 0, stream>>>(qw_gu, qtgu, HIDC / 32, NWGU / 8);
  repack_kernel<<<2048, 256, 0, stream>>>(qw_dn, qtdn, INTERC / 32, HIDC / 8);
  mktab_kernel<<<1024, 256, 0, stream>>>(qz_gu, sc_gu, tgu, (HIDC / 128) * NWGU, NWGU);
  mktab_kernel<<<1024, 256, 0, stream>>>(qz_dn, sc_dn, tdn, (INTERC / 128) * HIDC, HIDC);

  // GEMM1: x[4096x4096] @ W_gu -> silu*mul -> h f16 [4096x11008]; 86x16=1376 blocks
  qgemm_kernel<1, 64, NWGU, 86, HIDC>
      <<<1376, 512, 0, stream>>>(xh, qtgu, tgu, hbuf, nullptr);
  // GEMM2: h @ W_dn -> out f32 [4096x4096]; 16x16=256 blocks
  qgemm_kernel<0, 172, HIDC, 16, INTERC>
      <<<256, 512, 0, stream>>>(hbuf, qtdn, tdn, nullptr, out);
}

// Round 6
// 1390.307 us; speedup vs baseline: 6.7200x; 1.0002x over previous
//
#include <hip/hip_runtime.h>
#include <hip/hip_bf16.h>
#include <hip/hip_fp16.h>
#include <cstdint>
#include <cstddef>

#define AS1 __attribute__((address_space(1)))
#define AS3 __attribute__((address_space(3)))

constexpr int HIDC   = 4096;
constexpr int INTERC = 11008;
constexpr int NTOKC  = 4096;          // B*S
constexpr int NWGU   = 2 * INTERC;    // 22016 gate_up weight cols

using f32x4 = __attribute__((ext_vector_type(4))) float;
using f16x8 = __attribute__((ext_vector_type(8))) _Float16;

// ---------------- prologue kernels ----------------

__global__ void cvt_x_kernel(const float4* __restrict__ x, ushort4* __restrict__ xh, int n4) {
  int stride = gridDim.x * blockDim.x;
  for (int i = blockIdx.x * blockDim.x + threadIdx.x; i < n4; i += stride) {
    float4 v = x[i];
    ushort4 o;
    o.x = __builtin_bit_cast(unsigned short, __float2half(v.x));
    o.y = __builtin_bit_cast(unsigned short, __float2half(v.y));
    o.z = __builtin_bit_cast(unsigned short, __float2half(v.z));
    o.w = __builtin_bit_cast(unsigned short, __float2half(v.w));
    xh[i] = o;
  }
}

// repack qweight [K][N/8] (nibbles along N) -> qt [K/32][N][4] (k-tile-major).
// Nibble order within each qword PERMUTED: k=j at pos (j&1)?4+(j>>1):(j>>1),
// so (q>>4i)&0x000F000F extracts the k-pair (2i,2i+1).
__global__ void repack_kernel(const uint32_t* __restrict__ qw, uint32_t* __restrict__ qt,
                              int K32, int Wn8) {
  long total  = (long)K32 * Wn8;
  long stride = (long)gridDim.x * blockDim.x;
  for (long idx = blockIdx.x * (long)blockDim.x + threadIdx.x; idx < total; idx += stride) {
    int kt2 = (int)(idx / Wn8);
    int cg  = (int)(idx - (long)kt2 * Wn8);
    uint32_t ow[8][4] = {};
#pragma unroll
    for (int kl = 0; kl < 32; ++kl) {
      uint32_t v = qw[(size_t)(kt2 * 32 + kl) * Wn8 + cg];
      const int kkl = kl >> 3, j = kl & 7;
      const int pos = (j & 1) ? (4 + (j >> 1)) : (j >> 1);
#pragma unroll
      for (int c = 0; c < 8; ++c)
        ow[c][kkl] |= ((v >> (4 * c)) & 0xFu) << (4 * pos);
    }
    uint4* dst = (uint4*)(qt + ((size_t)kt2 * Wn8 * 8 + (size_t)cg * 8) * 4);
#pragma unroll
    for (int c = 0; c < 8; ++c)
      dst[c] = make_uint4(ow[c][0], ow[c][1], ow[c][2], ow[c][3]);
  }
}

// tab[g][n] = ( half2(s,s), half2(-z*s,-z*s) ) packed as uint2
__global__ void mktab_kernel(const uint32_t* __restrict__ qz, const float* __restrict__ sc,
                             uint2* __restrict__ tab, int total, int Nw) {
  int stride = gridDim.x * blockDim.x;
  for (int idx = blockIdx.x * blockDim.x + threadIdx.x; idx < total; idx += stride) {
    int g = idx / Nw, n = idx - g * Nw;
    uint32_t z = (qz[(size_t)g * (Nw >> 3) + (n >> 3)] >> ((n & 7) * 4)) & 0xFu;
    float s = sc[idx];
    uint32_t us = (uint32_t)__builtin_bit_cast(unsigned short, __float2half(s));
    uint32_t uc = (uint32_t)__builtin_bit_cast(unsigned short, __float2half(-s * (float)z));
    tab[idx] = make_uint2(us | (us << 16), uc | (uc << 16));
  }
}

// -------- fused dequant GEMM, 256x256, read-ahead 4-phase pipeline --------
// 512 threads = 8 waves (2M x 4N), per-wave 128x64 out, BK=64.
// Per phase: {stage slice} -> s_barrier -> {issue ds_reads for phase p+1}
// -> s_waitcnt lgkmcnt(len(R_{p+1})) -> sched_barrier -> MFMA_p.
// One barrier/phase; counted lgkm (in-order LDS retire covers older read set +
// dequant ds_write); counted vmcnt(2) once per tile (q/tab stay in flight).

#define BAR asm volatile("s_barrier" ::: "memory")
#define WAITL(N) asm volatile("s_waitcnt lgkmcnt(" #N ")" ::: "memory")

#define GLOAD(i, KT, DBUF)                                                       \
  __builtin_amdgcn_global_load_lds(                                              \
      (const AS1 uint32_t*)(A + a_src[i] + ((KT) + 1) * 64),                     \
      (AS3 uint32_t*)(lds + (DBUF) * 65536 + (i) * 8192 + w * 1024), 16, 0, 0)

#define DEQ_WORD(p, DSTBUF)                                                      \
  {                                                                              \
    char* bd_ = lds + (DSTBUF) * 65536 + boff;                                   \
    uint32_t r_[4];                                                              \
    _Pragma("unroll")                                                            \
    for (int i_ = 0; i_ < 4; ++i_) {                                             \
      uint32_t pr_ = ((qw_[p] >> (4 * i_)) & 0x000F000Fu) | 0x64006400u;         \
      __half2 t_  = __hsub2(__builtin_bit_cast(__half2, pr_), kk1024_);          \
      __half2 wv_ = __hfma2(t_, s2_, c2_);                                       \
      r_[i_] = __builtin_bit_cast(uint32_t, wv_);                                \
    }                                                                            \
    *(uint4*)(bd_ + (((kh) * 64 + (p) * 16) ^ bswz)) =                           \
        make_uint4(r_[0], r_[1], r_[2], r_[3]);                                  \
  }

#define RD_AV(SET, BUF, KK, MH)                                                  \
  {                                                                              \
    const int bb_ = ((((KK) * 4) | fq) ^ (fr & 7)) << 4;                         \
    const char* rb_ = lds + (BUF) * 65536 + a_rd_base + bb_;                     \
    _Pragma("unroll")                                                            \
    for (int j_ = 0; j_ < 4; ++j_)                                               \
      SET[j_] = *(const f16x8*)(rb_ + ((MH) * 4 + j_) * 2048);                   \
  }

#define RD_BV(SET, BUF, KK)                                                      \
  {                                                                              \
    const int bb_ = ((((KK) * 4) | fq) ^ (fr & 7)) << 4;                         \
    const char* rb_ = lds + (BUF) * 65536 + b_rd_base + bb_;                     \
    _Pragma("unroll")                                                            \
    for (int n_ = 0; n_ < 4; ++n_)                                               \
      SET[n_] = *(const f16x8*)(rb_ + n_ * 2048);                                \
  }

#define MFMA16(AV, BV, BLK)                                                      \
  __builtin_amdgcn_sched_barrier(0);                                             \
  __builtin_amdgcn_s_setprio(1);                                                 \
  _Pragma("unroll")                                                              \
  for (int j_ = 0; j_ < 4; ++j_)                                                 \
    _Pragma("unroll")                                                            \
    for (int n_ = 0; n_ < 4; ++n_)                                               \
      acc[(BLK) * 4 + j_][n_] = __builtin_amdgcn_mfma_f32_16x16x32_f16(          \
          AV[j_], BV[n_], acc[(BLK) * 4 + j_][n_], 0, 0, 0);                     \
  __builtin_amdgcn_s_setprio(0);

// One K-tile = 4 phases. Reads for this tile's phase 0 (avE,bvA) were issued
// at the end of the PREVIOUS tile (or prologue).
#define TILE(CUR, QUSE, TUSE, QLAND, TLAND, KT, STG, PRF, LAST)                  \
  {                                                                              \
    const int cur_ = (CUR);                                                      \
    const __half2 kk1024_ = __builtin_bit_cast(__half2, 0x64006400u);            \
    uint32_t qw_[4] = {};                                                        \
    __half2 s2_ = kk1024_, c2_ = kk1024_;                                        \
    if (STG) {                                                                   \
      qw_[0] = (QUSE).x; qw_[1] = (QUSE).y; qw_[2] = (QUSE).z; qw_[3] = (QUSE).w;\
      s2_ = __builtin_bit_cast(__half2, (TUSE).x);                               \
      c2_ = __builtin_bit_cast(__half2, (TUSE).y);                               \
    }                                                                            \
    /* phase 0: MFMA(kk0,mh0) */                                                 \
    if (STG) { GLOAD(0, KT, cur_ ^ 1); GLOAD(1, KT, cur_ ^ 1); DEQ_WORD(0, cur_ ^ 1) } \
    BAR;                                                                         \
    RD_AV(avO, cur_, 0, 1)                                                       \
    WAITL(4);                                                                    \
    MFMA16(avE, bvA, 0)                                                          \
    /* phase 1: MFMA(kk0,mh1) */                                                 \
    if (STG) { GLOAD(2, KT, cur_ ^ 1); GLOAD(3, KT, cur_ ^ 1); DEQ_WORD(1, cur_ ^ 1) } \
    BAR;                                                                         \
    RD_AV(avE, cur_, 1, 0)                                                       \
    RD_BV(bvB, cur_, 1)                                                          \
    WAITL(8);                                                                    \
    MFMA16(avO, bvA, 1)                                                          \
    /* phase 2: MFMA(kk1,mh0) */                                                 \
    if (STG) {                                                                   \
      if (PRF) { QLAND = *qaddr((KT) + 2);                                       \
                 TLAND = *taddr((KT) + 2); }                                     \
      DEQ_WORD(2, cur_ ^ 1)                                                      \
    }                                                                            \
    BAR;                                                                         \
    RD_AV(avO, cur_, 1, 1)                                                       \
    WAITL(4);                                                                    \
    MFMA16(avE, bvB, 0)                                                          \
    /* phase 3: MFMA(kk1,mh1); tile-boundary drain + read-ahead of next tile */  \
    if (STG) { DEQ_WORD(3, cur_ ^ 1) }                                           \
    if ((STG) && (PRF))                                                          \
      asm volatile("s_waitcnt vmcnt(2) lgkmcnt(0)" ::: "memory");                \
    else if (STG)                                                                \
      asm volatile("s_waitcnt vmcnt(0) lgkmcnt(0)" ::: "memory");                \
    else                                                                         \
      asm volatile("s_waitcnt lgkmcnt(0)" ::: "memory");                         \
    BAR;                                                                         \
    if (!(LAST)) {                                                               \
      RD_AV(avE, cur_ ^ 1, 0, 0)                                                 \
      RD_BV(bvA, cur_ ^ 1, 0)                                                    \
      WAITL(8);                                                                  \
    }                                                                            \
    MFMA16(avO, bvB, 1)                                                          \
  }

template <int DUAL, int NT, int NWTOT, int NXT, int K>
__global__ __launch_bounds__(512, 1) void qgemm_kernel(
    const __half* __restrict__ A, const uint32_t* __restrict__ QT,
    const uint2* __restrict__ TAB, __half* __restrict__ Hout,
    float* __restrict__ Fout) {
  __shared__ __align__(16) char lds[131072];

  const int tid  = threadIdx.x;
  const int lane = tid & 63;
  const int w    = tid >> 6;
  const int wr   = w >> 2, wc = w & 3;
  const int fr   = lane & 15;
  const int fq   = lane >> 4;

  // bijective XCD chunking (grid%8==0): N varies fastest within a chunk.
  const int nwg8 = (int)gridDim.x >> 3;
  const int g2   = (blockIdx.x & 7) * nwg8 + ((int)blockIdx.x >> 3);
  const int mt   = g2 / NXT;
  const int nt   = g2 - mt * NXT;
  const int row0 = mt * 256;

  // A staging: linear LDS dest, pre-swizzled global source (swz byte^=(row&7)<<4).
  int a_src[4];
#pragma unroll
  for (int i = 0; i < 4; ++i) {
    int o = i * 8192 + tid * 16;
    int r = o >> 7;
    int b = (o & 127) ^ ((r & 7) << 4);
    a_src[i] = (row0 + r) * K + (b >> 1);
  }

  // B staging: thread owns tile-col tc, k-half kh (one uint4 = 32 nibbles).
  const int tc = tid & 255, kh = tid >> 8;
  int wcol;
  if (DUAL) {
    const int p = tc >> 5, mat = (tc >> 4) & 1, c16 = tc & 15;
    wcol = nt * 128 + p * 16 + c16 + mat * INTERC;
  } else {
    wcol = nt * 256 + tc;
  }
  const int boff = 32768 + tc * 128;
  const int bswz = (tc & 7) << 4;

  const int a_rd_base = (wr * 128 + fr) * 128;
  const int b_rd_base = 32768 + (wc * 64 + fr) * 128;

  auto qaddr = [&](int t) {
    return (const uint4*)(QT + ((size_t)(2 * t + kh) * NWTOT + wcol) * 4);
  };
  auto taddr = [&](int t) { return TAB + (size_t)(t >> 1) * NWTOT + wcol; };

  f32x4 acc[8][4] = {};
  f16x8 avE[4], avO[4], bvA[4], bvB[4];

  // ---- prologue: tile 0 into buf0; q(1) in flight; read-ahead R_0 ----
  uint4 qA, qB; uint2 tA, tB;
  { GLOAD(0, -1, 0); GLOAD(1, -1, 0); GLOAD(2, -1, 0); GLOAD(3, -1, 0); }
  __builtin_amdgcn_sched_barrier(0);   // pin: stages before q loads (vmcnt order)
  uint4 q0  = *qaddr(0);
  uint2 t0v = *taddr(0);
  qB = *qaddr(1);
  tB = *taddr(1);
  __builtin_amdgcn_sched_barrier(0);
  {
    const __half2 kk1024_ = __builtin_bit_cast(__half2, 0x64006400u);
    const __half2 s2_ = __builtin_bit_cast(__half2, t0v.x);
    const __half2 c2_ = __builtin_bit_cast(__half2, t0v.y);
    uint32_t qw_[4] = {q0.x, q0.y, q0.z, q0.w};
    DEQ_WORD(0, 0) DEQ_WORD(1, 0) DEQ_WORD(2, 0) DEQ_WORD(3, 0)
  }
  asm volatile("s_waitcnt vmcnt(2) lgkmcnt(0)" ::: "memory");  // gloads+q0 retired; qB,tB in flight
  BAR;
  RD_AV(avE, 0, 0, 0)      // R_0 for tile 0 (buf0 fully staged after barrier)
  RD_BV(bvA, 0, 0)

  // ---- main loop: 2 tiles per iteration ----
#pragma unroll 1
  for (int kt2 = 0; kt2 < NT / 2 - 1; ++kt2) {
    TILE(0, qB, tB, qA, tA, 2 * kt2, 1, 1, 0)
    TILE(1, qA, tA, qB, tB, 2 * kt2 + 1, 1, 1, 0)
  }
  TILE(0, qB, tB, qA, tA, NT - 2, 1, 0, 0)
  TILE(1, qA, tA, qB, tB, NT - 1, 0, 0, 1)

  // ---- epilogue — C/D map: col = lane&15 (fr), row = fq*4 + reg ----
  if (DUAL) {
#pragma unroll
    for (int mi = 0; mi < 8; ++mi) {
      const int rr = row0 + wr * 128 + mi * 16 + fq * 4;
#pragma unroll
      for (int pp = 0; pp < 2; ++pp) {
        const int hcol = nt * 128 + (wc * 2 + pp) * 16 + fr;
#pragma unroll
        for (int r = 0; r < 4; ++r) {
          float gv = acc[mi][2 * pp][r];
          float uv = acc[mi][2 * pp + 1][r];
          float hv = gv / (1.0f + __expf(-gv)) * uv;
          Hout[(size_t)(rr + r) * INTERC + hcol] = __float2half(hv);
        }
      }
    }
  } else {
#pragma unroll
    for (int mi = 0; mi < 8; ++mi) {
      const int rr = row0 + wr * 128 + mi * 16 + fq * 4;
#pragma unroll
      for (int ni = 0; ni < 4; ++ni) {
        const int cc = nt * 256 + wc * 64 + ni * 16 + fr;
#pragma unroll
        for (int r = 0; r < 4; ++r)
          Fout[(size_t)(rr + r) * HIDC + cc] = acc[mi][ni][r];
      }
    }
  }
}

// ---------------- launch ----------------
extern "C" void kernel_launch(void* const* d_in, const int* in_sizes, int n_in,
                              void* d_out, int out_size, void* d_ws, size_t ws_size,
                              hipStream_t stream) {
  const float*    x     = (const float*)d_in[0];
  const uint32_t* qw_gu = (const uint32_t*)d_in[1];
  const uint32_t* qz_gu = (const uint32_t*)d_in[2];
  const float*    sc_gu = (const float*)d_in[3];
  const uint32_t* qw_dn = (const uint32_t*)d_in[4];
  const uint32_t* qz_dn = (const uint32_t*)d_in[5];
  const float*    sc_dn = (const float*)d_in[6];
  float* out = (float*)d_out;

  // workspace layout (bytes), ~199.8 MB
  char* ws = (char*)d_ws;
  __half*   xh   = (__half*)(ws + 0);                 // 33,554,432
  uint32_t* qtgu = (uint32_t*)(ws + 33554432);        // 45,088,768
  uint32_t* qtdn = (uint32_t*)(ws + 78643200);        // 22,544,384
  uint2*    tgu  = (uint2*)(ws + 101187584);          //  5,636,096
  uint2*    tdn  = (uint2*)(ws + 106823680);          //  2,818,048
  __half*   hbuf = (__half*)(ws + 109641728);         // 90,177,536

  cvt_x_kernel<<<2048, 256, 0, stream>>>((const float4*)x, (ushort4*)xh, NTOKC * HIDC / 4);
  repack_kernel<<<2048, 256, 0, stream>>>(qw_gu, qtgu, HIDC / 32, NWGU / 8);
  repack_kernel<<<2048, 256, 0, stream>>>(qw_dn, qtdn, INTERC / 32, HIDC / 8);
  mktab_kernel<<<1024, 256, 0, stream>>>(qz_gu, sc_gu, tgu, (HIDC / 128) * NWGU, NWGU);
  mktab_kernel<<<1024, 256, 0, stream>>>(qz_dn, sc_dn, tdn, (INTERC / 128) * HIDC, HIDC);

  // GEMM1: x[4096x4096] @ W_gu -> silu*mul -> h f16 [4096x11008]; 1376 blocks
  qgemm_kernel<1, 64, NWGU, 86, HIDC>
      <<<1376, 512, 0, stream>>>(xh, qtgu, tgu, hbuf, nullptr);
  // GEMM2: h @ W_dn -> out f32 [4096x4096]; 256 blocks
  qgemm_kernel<0, 172, HIDC, 16, INTERC>
      <<<256, 512, 0, stream>>>(hbuf, qtdn, tdn, nullptr, out);
}